// Round 4
// baseline (81.628 us; speedup 1.0000x reference)
//
#include <hip/hip_runtime.h>

#define I0F 5.6e-06f

// ---------------------------------------------------------------------------
// Single fused kernel.
//
//   Block 0, wave 0  : sequential SIR scan with early termination, writes
//                      out[0..t_stop), then publishes {t_stop, y_final} via a
//                      release-store of a tagged word in ws.
//   Blocks 1..255    : spin (acquire-load + s_sleep) on the tag, then fill
//                      out[t_stop..T) with y_final, grid-strided.
//
// Tag protocol: ws[0] = 0x40000000 | t_stop  (t_stop < 2^19, so tag >> 28 == 4
//   iff published). 0xAA poison (0xAAAAAAAA) and zeros both fail the check, so
//   no ws initialization is needed. ws[1] = y_final bits, ordered by the
//   release/acquire pair (read with a relaxed agent-scope atomic to bypass L1).
//
// Scan per 64-step chunk:
//   1. 64 lanes load rows t-1+lane (24 B each, lane-contiguous -> coalesced),
//      compute ct = row.b in parallel.
//   2. prefetch next chunk's rows (latency hidden under the serial chain).
//   3. broadcast 64 ct via __shfl (independent, hoisted), then 64-step serial
//      recurrence redundantly in all lanes:
//        i2 = fma(i*c, s, i*(1-k)) ; r2 = fma(k, i, r) ; s = (1-r2)-i2 ;
//        y  = i2 + r2
//      (algebraically the reference's i + i*c*s - k*i; fp reorder ~1e-7,
//      damped by the contracting dynamics; threshold is 1.83e-2).
//      Each step, lane u latches y via cndmask; one coalesced 64-lane store
//      per chunk.
//   4. early-stop check once per chunk.
//
// Early-stop soundness (static bound, no measured c_max):
//   x in [0,1) => c_t <= cb := sum_j max(b_j,0). r monotone non-decreasing =>
//   all future s <= 1-r_now. Stop when i==0 (frozen exactly) or i < 1e-5 and
//   cb*(1-r) < 0.9*k: future growth factor <= 1-k+cb*(1-r) <= 1-0.1k < 1
//   (geometric decay forever), total future |dy| = sum i*c*s <=
//   i*cb*(1-r)/(k-cb*(1-r)) <= 1e-5*0.9k/(0.1k) = 9e-5 << 1.83e-2.
// ---------------------------------------------------------------------------
__global__ __launch_bounds__(256) void sir_kernel(const float* __restrict__ x,
                                                  const float* __restrict__ bv,
                                                  const float* __restrict__ kv,
                                                  float* __restrict__ out,
                                                  int T,
                                                  unsigned int* __restrict__ ws) {
    // ---------------- fill path: blocks 1..gridDim-1 ----------------
    if (blockIdx.x != 0) {
        unsigned int tag;
        do {
            tag = __hip_atomic_load(&ws[0], __ATOMIC_ACQUIRE, __HIP_MEMORY_SCOPE_AGENT);
            if ((tag >> 28) == 4u) break;
            __builtin_amdgcn_s_sleep(2);
        } while (true);
        const int   t_stop = (int)(tag & 0x0FFFFFFFu);
        const unsigned int yb =
            __hip_atomic_load(&ws[1], __ATOMIC_RELAXED, __HIP_MEMORY_SCOPE_AGENT);
        const float yf = __uint_as_float(yb);

        const int base   = (blockIdx.x - 1) * 256 + threadIdx.x;
        const int stride = (gridDim.x - 1) * 256;
        for (int idx = base; idx < T; idx += stride)
            if (idx >= t_stop) out[idx] = yf;
        return;
    }

    // ---------------- scan path: block 0, wave 0 ----------------
    if (threadIdx.x >= 64) return;
    const int lane = threadIdx.x;

    const float b0 = bv[0], b1 = bv[1], b2 = bv[2], b3 = bv[3], b4 = bv[4], b5 = bv[5];
    const float kq  = fabsf(kv[0]);
    const float omk = 1.0f - kq;
    const float cb  = fmaxf(b0, 0.0f) + fmaxf(b1, 0.0f) + fmaxf(b2, 0.0f) +
                      fmaxf(b3, 0.0f) + fmaxf(b4, 0.0f) + fmaxf(b5, 0.0f);
    const float thr = 0.90f * kq;

    float i = I0F;
    float r = 0.0f;
    float s = 1.0f - I0F;
    float y = I0F;                 // y_0 = i_0 + r_0 = i0
    if (lane == 0) out[0] = y;

    int  t      = 1;
    int  t_stop = T;
    bool done   = false;

    auto loadRow = [&](int row, float2& p0, float2& p1, float2& p2) {
        const float2* rp = reinterpret_cast<const float2*>(x + (size_t)row * 6);
        p0 = rp[0]; p1 = rp[1]; p2 = rp[2];
    };
    auto dot = [&](float2 p0, float2 p1, float2 p2) {
        return p0.x * b0 + p0.y * b1 + p1.x * b2 + p1.y * b3 + p2.x * b4 + p2.y * b5;
    };

    float ct = 0.0f;
    if (t + 64 <= T) {
        float2 q0, q1, q2;
        loadRow(t - 1 + lane, q0, q1, q2);     // rows t-1 .. t+62, all < T
        ct = dot(q0, q1, q2);
    }

    while (t + 64 <= T) {
        const bool have_next = (t + 128 <= T);
        float2 n0, n1, n2;
        if (have_next) loadRow(t + 63 + lane, n0, n1, n2);

        float cts[64];
#pragma unroll
        for (int u = 0; u < 64; ++u) cts[u] = __shfl(ct, u, 64);

        float ykeep = 0.0f;
#pragma unroll
        for (int u = 0; u < 64; ++u) {
            const float c  = cts[u];
            const float a  = i * c;
            const float i2 = fmaf(a, s, i * omk);       // i + i*c*s - k*i
            const float r2 = fmaf(kq, i, r);            // r + k*i
            s = (1.0f - r2) - i2;
            y = i2 + r2;
            i = i2;
            r = r2;
            ykeep = (lane == u) ? y : ykeep;            // latch step u's y in lane u
        }
        out[t + lane] = ykeep;                          // one coalesced store/chunk
        t += 64;

        if (i == 0.0f || (i < 1e-5f && cb * (1.0f - r) < thr)) {
            t_stop = t;
            done   = true;
            break;
        }
        if (!have_next) break;
        ct = dot(n0, n1, n2);
    }

    if (!done) {
        // scalar tail (partial final chunk, or full fallback if no convergence)
        while (t < T) {
            const float2* rp = reinterpret_cast<const float2*>(x + (size_t)(t - 1) * 6);
            const float2 p0 = rp[0], p1 = rp[1], p2 = rp[2];
            const float c  = dot(p0, p1, p2);
            const float a  = i * c;
            const float i2 = fmaf(a, s, i * omk);
            const float r2 = fmaf(kq, i, r);
            s = (1.0f - r2) - i2;
            y = i2 + r2;
            i = i2;
            r = r2;
            if (lane == 0) out[t] = y;
            ++t;
        }
        t_stop = T;
    }

    if (lane == 0) {
        __hip_atomic_store(&ws[1], __float_as_uint(y), __ATOMIC_RELAXED,
                           __HIP_MEMORY_SCOPE_AGENT);
        __hip_atomic_store(&ws[0], 0x40000000u | (unsigned int)t_stop,
                           __ATOMIC_RELEASE, __HIP_MEMORY_SCOPE_AGENT);
    }
}

extern "C" void kernel_launch(void* const* d_in, const int* in_sizes, int n_in,
                              void* d_out, int out_size, void* d_ws, size_t ws_size,
                              hipStream_t stream) {
    const float* x = (const float*)d_in[0];   // [T,6] f32
    const float* b = (const float*)d_in[1];   // [6,1] f32
    const float* k = (const float*)d_in[2];   // [1,1] f32
    float* out = (float*)d_out;               // [1,T] f32
    int T = out_size;                         // 262144

    unsigned int* ws = (unsigned int*)d_ws;   // ws[0]: tag|t_stop, ws[1]: y bits
    // No ws init needed: 0xAA poison fails the (tag>>28)==4 readiness check.

    sir_kernel<<<256, 256, 0, stream>>>(x, b, k, out, T, ws);
}

// Round 5
// 66.111 us; speedup vs baseline: 1.2347x; 1.2347x over previous
//
#include <hip/hip_runtime.h>

#define I0F 5.6e-06f

// ---------------------------------------------------------------------------
// Single fused kernel, fixed handshake (R4's spin caused an acquire-
// invalidation storm: 1020 pollers x acquire-load every ~180ns on one line).
//
//   Block 0, wave 0  : sequential SIR scan with early termination, writes
//                      out[0..t_stop), publishes ONE 64-bit word:
//                         tag64 = (y_bits << 32) | 0x40000000 | t_stop
//   Blocks 1..255    : ONE lane polls tag64 with a RELAXED agent-scope 64-bit
//                      load every s_sleep(32) (~2048 cyc); no acquire, no
//                      invalidations. Both values ride in one atomic word so
//                      no load-load ordering is needed. Rest of the block
//                      parks at __syncthreads. Then grid-stride fill of
//                      out[t_stop..T) with y_final.
//
//   Poison-safety: 0xAAAAAAAA low word has (w>>28)==0xA != 4; zeros fail too.
//   Deadlock-safety: 256 blocks x 256 thr, ~76 VGPR -> all co-resident on
//   256 CUs; scan always publishes (including the no-convergence fallback).
//
// Scan per 64-step chunk: 64 lanes load rows t-1+lane (coalesced 24 B/lane),
// dot with b in parallel; prefetch next chunk; broadcast 64 ct via __shfl;
// run the 64-step recurrence redundantly in all lanes:
//   i2 = fma(i*c, s, i*(1-k)); r2 = fma(k,i,r); s = (1-r2)-i2; y = i2+r2
// lane u latches step u's y; one coalesced store per chunk.
//
// Early-stop soundness: x in [0,1) => c_t <= cb := sum_j max(b_j,0); r is
// monotone => future s <= 1-r. Stop when i==0 (frozen exactly) or i < 1e-5
// and cb*(1-r) < 0.9*k: future factor <= 1-0.1k < 1 (geometric decay
// forever), total future |dy| <= i*cb*(1-r)/(k-cb*(1-r)) <= 9e-5 << 1.83e-2
// threshold. (Measured absmax 0.0 in R3/R4 with this rule.)
// ---------------------------------------------------------------------------
__global__ __launch_bounds__(256) void sir_kernel(const float* __restrict__ x,
                                                  const float* __restrict__ bv,
                                                  const float* __restrict__ kv,
                                                  float* __restrict__ out,
                                                  int T,
                                                  unsigned long long* __restrict__ ws) {
    // ---------------- fill path: blocks 1..gridDim-1 ----------------
    if (blockIdx.x != 0) {
        __shared__ unsigned long long sh_tag;
        if (threadIdx.x == 0) {
            unsigned long long tag;
            for (;;) {
                tag = __hip_atomic_load(ws, __ATOMIC_RELAXED, __HIP_MEMORY_SCOPE_AGENT);
                if (((unsigned int)tag >> 28) == 4u) break;
                __builtin_amdgcn_s_sleep(32);
            }
            sh_tag = tag;
        }
        __syncthreads();
        const unsigned long long tag = sh_tag;
        const int   t_stop = (int)((unsigned int)tag & 0x0FFFFFFFu);
        const float yf     = __uint_as_float((unsigned int)(tag >> 32));

        const int base   = (blockIdx.x - 1) * 256 + threadIdx.x;
        const int stride = (gridDim.x - 1) * 256;
        for (int idx = base; idx < T; idx += stride)
            if (idx >= t_stop) out[idx] = yf;
        return;
    }

    // ---------------- scan path: block 0, wave 0 ----------------
    if (threadIdx.x >= 64) return;
    const int lane = threadIdx.x;

    const float b0 = bv[0], b1 = bv[1], b2 = bv[2], b3 = bv[3], b4 = bv[4], b5 = bv[5];
    const float kq  = fabsf(kv[0]);
    const float omk = 1.0f - kq;
    const float cb  = fmaxf(b0, 0.0f) + fmaxf(b1, 0.0f) + fmaxf(b2, 0.0f) +
                      fmaxf(b3, 0.0f) + fmaxf(b4, 0.0f) + fmaxf(b5, 0.0f);
    const float thr = 0.90f * kq;

    float i = I0F;
    float r = 0.0f;
    float s = 1.0f - I0F;
    float y = I0F;                 // y_0 = i_0 + r_0 = i0
    if (lane == 0) out[0] = y;

    int  t      = 1;
    int  t_stop = T;
    bool done   = false;

    auto loadRow = [&](int row, float2& p0, float2& p1, float2& p2) {
        const float2* rp = reinterpret_cast<const float2*>(x + (size_t)row * 6);
        p0 = rp[0]; p1 = rp[1]; p2 = rp[2];
    };
    auto dot = [&](float2 p0, float2 p1, float2 p2) {
        return p0.x * b0 + p0.y * b1 + p1.x * b2 + p1.y * b3 + p2.x * b4 + p2.y * b5;
    };

    float ct = 0.0f;
    if (t + 64 <= T) {
        float2 q0, q1, q2;
        loadRow(t - 1 + lane, q0, q1, q2);     // rows t-1 .. t+62, all < T
        ct = dot(q0, q1, q2);
    }

    while (t + 64 <= T) {
        const bool have_next = (t + 128 <= T);
        float2 n0, n1, n2;
        if (have_next) loadRow(t + 63 + lane, n0, n1, n2);

        float cts[64];
#pragma unroll
        for (int u = 0; u < 64; ++u) cts[u] = __shfl(ct, u, 64);

        float ykeep = 0.0f;
#pragma unroll
        for (int u = 0; u < 64; ++u) {
            const float c  = cts[u];
            const float a  = i * c;
            const float i2 = fmaf(a, s, i * omk);       // i + i*c*s - k*i
            const float r2 = fmaf(kq, i, r);            // r + k*i
            s = (1.0f - r2) - i2;
            y = i2 + r2;
            i = i2;
            r = r2;
            ykeep = (lane == u) ? y : ykeep;            // latch step u's y in lane u
        }
        out[t + lane] = ykeep;                          // one coalesced store/chunk
        t += 64;

        if (i == 0.0f || (i < 1e-5f && cb * (1.0f - r) < thr)) {
            t_stop = t;
            done   = true;
            break;
        }
        if (!have_next) break;
        ct = dot(n0, n1, n2);
    }

    if (!done) {
        // scalar tail (partial final chunk, or full fallback if no convergence)
        while (t < T) {
            const float2* rp = reinterpret_cast<const float2*>(x + (size_t)(t - 1) * 6);
            const float2 p0 = rp[0], p1 = rp[1], p2 = rp[2];
            const float c  = dot(p0, p1, p2);
            const float a  = i * c;
            const float i2 = fmaf(a, s, i * omk);
            const float r2 = fmaf(kq, i, r);
            s = (1.0f - r2) - i2;
            y = i2 + r2;
            i = i2;
            r = r2;
            if (lane == 0) out[t] = y;
            ++t;
        }
        t_stop = T;
    }

    if (lane == 0) {
        const unsigned long long tag =
            ((unsigned long long)__float_as_uint(y) << 32) |
            0x40000000u | (unsigned int)t_stop;
        __hip_atomic_store(ws, tag, __ATOMIC_RELEASE, __HIP_MEMORY_SCOPE_AGENT);
    }
}

extern "C" void kernel_launch(void* const* d_in, const int* in_sizes, int n_in,
                              void* d_out, int out_size, void* d_ws, size_t ws_size,
                              hipStream_t stream) {
    const float* x = (const float*)d_in[0];   // [T,6] f32
    const float* b = (const float*)d_in[1];   // [6,1] f32
    const float* k = (const float*)d_in[2];   // [1,1] f32
    float* out = (float*)d_out;               // [1,T] f32
    int T = out_size;                         // 262144

    unsigned long long* ws = (unsigned long long*)d_ws;  // packed {y_bits, tag|t_stop}
    // No ws init needed: 0xAAAAAAAA low word fails the (w>>28)==4 readiness check.

    sir_kernel<<<256, 256, 0, stream>>>(x, b, k, out, T, ws);
}